// Round 20
// baseline (103.845 us; speedup 1.0000x reference)
//
#include <hip/hip_runtime.h>
#include <hip/hip_bf16.h>

typedef __attribute__((ext_vector_type(4))) float f32x4;
typedef __attribute__((ext_vector_type(8))) short bf16x8;

// Problem constants (B=2, S=2048, D=1024, H=16, DK=64)
#define Bn 2
#define Sn 2048
#define Dn 1024
#define Hn 16
#define DKn 64
#define Mrows (Bn * Sn)   // 4096

__device__ __forceinline__ unsigned short f2bf(float f) {
  unsigned int x = __float_as_uint(f);
  x += 0x7fffu + ((x >> 16) & 1u);   // round-to-nearest-even
  return (unsigned short)(x >> 16);
}

__device__ __forceinline__ float bf2f(unsigned short u) {
  return __uint_as_float(((unsigned int)u) << 16);
}

__device__ __forceinline__ unsigned int cvtpk(float lo, float hi) {
  unsigned int r;
  asm("v_cvt_pk_bf16_f32 %0, %1, %2" : "=v"(r) : "v"(lo), "v"(hi));
  return r;
}

__device__ __forceinline__ float exp2a(float x) {   // native v_exp_f32 (2^x)
  float r;
  asm("v_exp_f32 %0, %1" : "=v"(r) : "v"(x));
  return r;
}

__device__ __forceinline__ f32x4 mfma16(bf16x8 a, bf16x8 b, f32x4 c) {
  return __builtin_amdgcn_mfma_f32_16x16x32_bf16(a, b, c, 0, 0, 0);
}

__device__ __forceinline__ f32x4 max4(f32x4 a, f32x4 b) {
  f32x4 r;
  r[0] = fmaxf(a[0], b[0]); r[1] = fmaxf(a[1], b[1]);
  r[2] = fmaxf(a[2], b[2]); r[3] = fmaxf(a[3], b[3]);
  return r;
}

__device__ __forceinline__ void gload_lds16(const unsigned short* g, unsigned short* l) {
  __builtin_amdgcn_global_load_lds(
      (const __attribute__((address_space(1))) void*)g,
      (__attribute__((address_space(3))) void*)l, 16, 0, 0);
}

// ---------------------------------------------------------------------------
// fused fp32 -> bf16 convert for x + 4 weights (one launch)
// ---------------------------------------------------------------------------
__global__ __launch_bounds__(256)
void cvt_all(const float* __restrict__ x,  const float* __restrict__ wq,
             const float* __restrict__ wk, const float* __restrict__ wv,
             const float* __restrict__ wo,
             unsigned short* __restrict__ xb,  unsigned short* __restrict__ wqb,
             unsigned short* __restrict__ wkb, unsigned short* __restrict__ wvb,
             unsigned short* __restrict__ wob) {
  int i = (blockIdx.x * 256 + threadIdx.x) * 4;
  const float* src; unsigned short* dst; int off;
  int r = i >> 20;
  if (r < 4)       { src = x;  dst = xb;  off = i; }
  else if (r == 4) { src = wq; dst = wqb; off = i & 1048575; }
  else if (r == 5) { src = wk; dst = wkb; off = i & 1048575; }
  else if (r == 6) { src = wv; dst = wvb; off = i & 1048575; }
  else             { src = wo; dst = wob; off = i & 1048575; }
  float4 v = *(const float4*)(src + off);
  ushort4 o;
  o.x = f2bf(v.x); o.y = f2bf(v.y); o.z = f2bf(v.z); o.w = f2bf(v.w);
  *(ushort4*)(dst + off) = o;
}

// ---------------------------------------------------------------------------
// 128x128-tile QKV GEMM, 8 WAVES (512 threads, wave-tile 32x64): BK=32,
// TRIPLE-buffered LDS (48 KB, 3 blocks/CU = 24 waves/CU), 1 raw barrier per
// step + counted vmcnt(2) (2 gloads/wave/stage, 2 stages in flight).
// Granule-XOR swizzle both sides.
// MODE 0: bf16, scaled 0.125*log2(e) (Q, exp2 domain) | 1: bf16 (K)
// MODE 2: bf16 Vt[b][h][d][s] transposed
// ---------------------------------------------------------------------------
template<int MODE>
__device__ __forceinline__ void gemm_body8(const unsigned short* __restrict__ A,
                                           const unsigned short* __restrict__ W,
                                           unsigned short* __restrict__ Cb,
                                           unsigned short* As,   // [3][128*32]
                                           unsigned short* Bs,   // [3][128*32]
                                           int row0, int col0) {
  const int K = Dn, N = Dn;
  const int tid  = threadIdx.x;
  const int wid  = tid >> 6;               // 0..7
  const int lane = tid & 63;
  const int l15  = lane & 15;
  const int lg   = lane >> 4;
  const int wr = (wid >> 1) * 32;          // 4 M-waves x 32 rows
  const int wc = (wid & 1) * 64;           // 2 N-waves x 64 cols

  f32x4 acc[2][4] = {};

  const int lrow2 = lane >> 2;             // row within chunk 0..15
  const int gs    = (lane & 3) ^ ((lane >> 3) & 3);  // pre-swizzled src granule
  const int swzr  = (l15 >> 1) & 3;        // read-side XOR

  // 16 chunks: 0..7 = A rows (16 each), 8..15 = B rows (16 each); 2/wave.
  auto stage = [&](int kt, int b) {
#pragma unroll
    for (int q = 0; q < 2; ++q) {
      int id = wid * 2 + q;                // 0..15
      if (id < 8) {
        int r = id * 16 + lrow2;
        gload_lds16(A + (size_t)(row0 + r) * K + kt + gs * 8,
                    &As[b * 4096 + id * 512]);
      } else {
        int r = (id - 8) * 16 + lrow2;
        gload_lds16(W + (size_t)(col0 + r) * K + kt + gs * 8,
                    &Bs[b * 4096 + (id - 8) * 512]);
      }
    }
  };

  auto compute = [&](int b) {
    bf16x8 af[2], bfr[4];
#pragma unroll
    for (int m = 0; m < 2; ++m)
      af[m] = *(const bf16x8*)(&As[b * 4096 + (wr + m * 16 + l15) * 32 +
                                   ((lg ^ swzr) * 8)]);
#pragma unroll
    for (int n = 0; n < 4; ++n)
      bfr[n] = *(const bf16x8*)(&Bs[b * 4096 + (wc + n * 16 + l15) * 32 +
                                    ((lg ^ swzr) * 8)]);
    __builtin_amdgcn_s_setprio(1);
#pragma unroll
    for (int m = 0; m < 2; ++m)
#pragma unroll
      for (int n = 0; n < 4; ++n)
        acc[m][n] = mfma16(af[m], bfr[n], acc[m][n]);
    __builtin_amdgcn_s_setprio(0);
  };

  stage(0, 0);
  stage(32, 1);
  int cb = 0;
#pragma unroll 1
  for (int t = 0; t < 32; ++t) {
    if (t < 31) asm volatile("s_waitcnt vmcnt(2)" ::: "memory");
    else        asm volatile("s_waitcnt vmcnt(0)" ::: "memory");
    __builtin_amdgcn_sched_barrier(0);
    __builtin_amdgcn_s_barrier();
    __builtin_amdgcn_sched_barrier(0);
    if (t <= 29) {
      int sb = cb + 2; if (sb >= 3) sb -= 3;
      stage((t + 2) * 32, sb);
    }
    compute(cb);
    ++cb; if (cb == 3) cb = 0;
  }

#pragma unroll
  for (int m = 0; m < 2; ++m)
#pragma unroll
    for (int n = 0; n < 4; ++n) {
      int r0 = row0 + wr + m * 16 + lg * 4;
      int c  = col0 + wc + n * 16 + l15;
      if (MODE == 2) {
        int b = r0 >> 11, s = r0 & 2047;
        int h = c >> 6,  d = c & 63;
        ushort4 pw;
        pw.x = f2bf(acc[m][n][0]); pw.y = f2bf(acc[m][n][1]);
        pw.z = f2bf(acc[m][n][2]); pw.w = f2bf(acc[m][n][3]);
        *(ushort4*)(Cb + ((((size_t)b * Hn + h) * DKn + d) << 11) + s) = pw;
      } else {
        const float sc = (MODE == 0) ? 0.18033688f : 1.0f;  // Q: 0.125*log2e
#pragma unroll
        for (int j = 0; j < 4; ++j)
          Cb[(size_t)(r0 + j) * N + c] = f2bf(acc[m][n][j] * sc);
      }
    }
}

// XCD panel mapping: fid%24 = panel (y = panel&7, z = panel>>3), fid/24 = x.
__global__ __launch_bounds__(512, 3)
void gemm_qkv(const unsigned short* __restrict__ A,
              const unsigned short* __restrict__ W0,
              const unsigned short* __restrict__ W1,
              const unsigned short* __restrict__ W2,
              unsigned short* __restrict__ C0,
              unsigned short* __restrict__ C1,
              unsigned short* __restrict__ C2) {
  __shared__ unsigned short As[3 * 128 * 32];
  __shared__ unsigned short Bs[3 * 128 * 32];
  const int fid = blockIdx.x;          // 0..767
  const int panel = fid % 24;
  const int row0 = (fid / 24) * 128;
  const int col0 = (panel & 7) * 128;
  const int z = panel >> 3;
  if (z == 0)      gemm_body8<0>(A, W0, C0, As, Bs, row0, col0);
  else if (z == 1) gemm_body8<1>(A, W1, C1, As, Bs, row0, col0);
  else             gemm_body8<2>(A, W2, C2, As, Bs, row0, col0);
}

// ---------------------------------------------------------------------------
// Output projection GEMM: 64x128 tiles, 512 blocks (2/CU exact, zero tail),
// BK=32, TRIPLE-buffered (36 KB), 1 barrier/step + counted vmcnt(3).
// Wave-tile 32x64; 12 staging chunks = 3 per wave.  fp32 output.
// ---------------------------------------------------------------------------
__global__ __launch_bounds__(256, 4)
void gemm_out(const unsigned short* __restrict__ A,
              const unsigned short* __restrict__ W,
              float* __restrict__ C) {
  __shared__ unsigned short As[3 * 64 * 32];    // 12 KB
  __shared__ unsigned short Bs[3 * 128 * 32];   // 24 KB
  const int K = Dn, N = Dn;
  const int tid  = threadIdx.x;
  const int wid  = tid >> 6;
  const int lane = tid & 63;
  const int l15  = lane & 15;
  const int lg   = lane >> 4;
  const int row0 = blockIdx.x * 64;
  const int col0 = blockIdx.y * 128;
  const int wr = (wid >> 1) * 32;
  const int wc = (wid & 1) * 64;

  f32x4 acc[2][4] = {};

  const int lrow2 = lane >> 2;               // row within chunk 0..15
  const int gs    = (lane & 3) ^ ((lane >> 3) & 3);  // pre-swizzled src granule
  const int swzr  = (l15 >> 1) & 3;          // read-side XOR

  // 12 chunks: 0..3 = A rows (16 each), 4..11 = B rows (16 each).
  auto stage = [&](int kt, int b) {
#pragma unroll
    for (int q = 0; q < 3; ++q) {
      int id = wid * 3 + q;                  // 0..11
      if (id < 4) {
        int r = id * 16 + lrow2;
        gload_lds16(A + (size_t)(row0 + r) * K + kt + gs * 8,
                    &As[b * 2048 + id * 512]);
      } else {
        int r = (id - 4) * 16 + lrow2;
        gload_lds16(W + (size_t)(col0 + r) * K + kt + gs * 8,
                    &Bs[b * 4096 + (id - 4) * 512]);
      }
    }
  };

  auto compute = [&](int b) {
    bf16x8 af[2], bfr[4];
#pragma unroll
    for (int m = 0; m < 2; ++m)
      af[m] = *(const bf16x8*)(&As[b * 2048 + (wr + m * 16 + l15) * 32 +
                                   ((lg ^ swzr) * 8)]);
#pragma unroll
    for (int n = 0; n < 4; ++n)
      bfr[n] = *(const bf16x8*)(&Bs[b * 4096 + (wc + n * 16 + l15) * 32 +
                                    ((lg ^ swzr) * 8)]);
    __builtin_amdgcn_s_setprio(1);
#pragma unroll
    for (int m = 0; m < 2; ++m)
#pragma unroll
      for (int n = 0; n < 4; ++n)
        acc[m][n] = mfma16(af[m], bfr[n], acc[m][n]);
    __builtin_amdgcn_s_setprio(0);
  };

  stage(0, 0);
  stage(32, 1);
  int cb = 0;
#pragma unroll 1
  for (int t = 0; t < 32; ++t) {
    if (t < 31) asm volatile("s_waitcnt vmcnt(3)" ::: "memory");
    else        asm volatile("s_waitcnt vmcnt(0)" ::: "memory");
    __builtin_amdgcn_sched_barrier(0);
    __builtin_amdgcn_s_barrier();
    __builtin_amdgcn_sched_barrier(0);
    if (t <= 29) {
      int sb = cb + 2; if (sb >= 3) sb -= 3;
      stage((t + 2) * 32, sb);
    }
    compute(cb);
    ++cb; if (cb == 3) cb = 0;
  }

#pragma unroll
  for (int m = 0; m < 2; ++m)
#pragma unroll
    for (int n = 0; n < 4; ++n) {
      int r0 = row0 + wr + m * 16 + lg * 4;
      int c  = col0 + wc + n * 16 + l15;
#pragma unroll
      for (int j = 0; j < 4; ++j)
        C[(size_t)(r0 + j) * N + c] = acc[m][n][j];
    }
}

// ---------------------------------------------------------------------------
// Flash attention (causal), swapped-operand, UNIFORM KV-SPLIT, QBLK=256.
// (round-16/19 structure, unchanged)
// ---------------------------------------------------------------------------
__global__ __launch_bounds__(512, 4)
void attn_part(const unsigned short* __restrict__ Qg,
               const unsigned short* __restrict__ Kg,
               const unsigned short* __restrict__ Vtg,
               unsigned short* __restrict__ Og,
               unsigned short* __restrict__ Pb,
               float* __restrict__ Pml) {
  const int bid = blockIdx.x;      // 0..511
  const int bh = bid & 31;         // bh%8 -> XCD locality
  const int j  = bid >> 5;         // 0..15: which 9-tile run
  const int bb = bh >> 4, hh = bh & 15;
  const int tid = threadIdx.x, wid = tid >> 6, lane = tid & 63;  // wid 0..7
  const int l15 = lane & 15, lg = lane >> 4;
  const int wq = wid * 32;
  const size_t baseQ = (size_t)bb * Sn * Dn + (size_t)hh * DKn;
  const size_t baseV = (size_t)bh * DKn * Sn;

  __shared__ unsigned short Ks[2][64 * 64];   // K tile  [key][d], parity dbuf
  __shared__ unsigned short Vts[2][64 * 64];  // Vt tile [d][key], parity dbuf
  __shared__ unsigned short Ps[8][32 * 72];   // per-wave P [q][key], pad 72

  const int lrow  = lane >> 3;
  const int sgran = (lane & 7) ^ lrow;
  const int swz   = l15 & 7;

  // locate starting segment: seg_s(qt) = 2qt(qt+1), len 4(qt+1)
  const int g0 = 9 * j;
  int qt = 0;
  while (2 * (qt + 1) * (qt + 2) <= g0) ++qt;
  int kt = g0 - 2 * qt * (qt + 1);

  int sqt = qt, skt = kt;
  auto stage = [&](int t, int b) {
    const int k0 = t << 6;
    gload_lds16(Kg + baseQ + (size_t)(k0 + wid * 8 + lrow) * Dn + sgran * 8,
                &Ks[b][wid * 512]);
    gload_lds16(Vtg + baseV + (size_t)(wid * 8 + lrow) * Sn + k0 + sgran * 8,
                &Vts[b][wid * 512]);
  };
  auto advs = [&]() { ++skt; if (skt == 4 * sqt + 4) { skt = 0; ++sqt; } };

  stage(skt, 0); advs();
  __syncthreads();

  bf16x8 qf[2][2];
  auto loadQ = [&](int qtile) {
    const int q0 = qtile * 256;
#pragma unroll
    for (int qm = 0; qm < 2; ++qm)
#pragma unroll
      for (int kd = 0; kd < 2; ++kd)
        qf[qm][kd] = *(const bf16x8*)(Qg + baseQ +
                     (size_t)(q0 + wq + qm * 16 + l15) * Dn + kd * 32 + lg * 8);
  };
  loadQ(qt);

  f32x4 oacc[2][4] = {};
  float mrun[2] = {-1e30f, -1e30f};
  float lrun[2] = {0.f, 0.f};     // per-lane partials (deferred cross-lane sum)
  int pstart = kt;                 // first kv-tile of current piece

  for (int i = 0; i < 9; ++i) {
    const int cur = i & 1;
    if (i < 8) { stage(skt, cur ^ 1); advs(); }
    const int k0 = kt << 6;
    const int q0 = qt << 8;

    if (k0 <= q0 + wq + 31) {      // wave-level causal skip (wave-uniform)
      f32x4 sf[2][4] = {};
      __builtin_amdgcn_s_setprio(1);
#pragma unroll
      for (int kn = 0; kn < 4; ++kn)
#pragma unroll
        for (int kd = 0; kd < 2; ++kd) {
          bf16x8 kf = *(const bf16x8*)(&Ks[cur][(kn * 16 + l15) * 64 +
                                              (((kd * 4 + lg) ^ swz) * 8)]);
          sf[0][kn] = mfma16(kf, qf[0][kd], sf[0][kn]);
          sf[1][kn] = mfma16(kf, qf[1][kd], sf[1][kn]);
        }
      __builtin_amdgcn_s_setprio(0);

      if (k0 + 63 > q0 + wq) {     // causal mask (diag-overlap tiles)
#pragma unroll
        for (int qm = 0; qm < 2; ++qm) {
          int qq = q0 + wq + qm * 16 + l15;
#pragma unroll
          for (int kn = 0; kn < 4; ++kn)
#pragma unroll
            for (int jj = 0; jj < 4; ++jj) {
              int key = k0 + kn * 16 + lg * 4 + jj;
              if (key > qq) sf[qm][kn][jj] = -1e30f;
            }
        }
      }

#pragma unroll
      for (int qm = 0; qm < 2; ++qm) {
        // lane-local max of own 16 values (no cross-lane in common path)
        f32x4 mm = max4(max4(sf[qm][0], sf[qm][1]), max4(sf[qm][2], sf[qm][3]));
        float tl = fmaxf(fmaxf(mm[0], mm[1]), fmaxf(mm[2], mm[3]));
        if (__any(tl > mrun[qm] + 11.5f)) {   // defer-max THR (log2 domain)
          float t = tl;
          t = fmaxf(t, __shfl_xor(t, 16));
          t = fmaxf(t, __shfl_xor(t, 32));
          float mnew = fmaxf(mrun[qm], t);
          float corr = exp2a(mrun[qm] - mnew);
          mrun[qm] = mnew;
          lrun[qm] *= corr;
#pragma unroll
          for (int dn = 0; dn < 4; ++dn) oacc[qm][dn] *= corr;
        }
        const float m = mrun[qm];
#pragma unroll
        for (int kn = 0; kn < 4; ++kn) {
#pragma unroll
          for (int jj = 0; jj < 4; ++jj)
            sf[qm][kn][jj] = exp2a(sf[qm][kn][jj] - m);
          uint2 pw;
          pw.x = cvtpk(sf[qm][kn][0], sf[qm][kn][1]);
          pw.y = cvtpk(sf[qm][kn][2], sf[qm][kn][3]);
          *(uint2*)(&Ps[wid][(qm * 16 + l15) * 72 + kn * 16 + lg * 4]) = pw;
        }
        f32x4 sv = (sf[qm][0] + sf[qm][1]) + (sf[qm][2] + sf[qm][3]);
        lrun[qm] += (sv[0] + sv[1]) + (sv[2] + sv[3]);   // per-lane partial
      }

      __builtin_amdgcn_s_setprio(1);
#pragma unroll
      for (int kk = 0; kk < 2; ++kk) {
        bf16x8 pf[2];
#pragma unroll
        for (int qm = 0; qm < 2; ++qm)
          pf[qm] = *(const bf16x8*)(&Ps[wid][(qm * 16 + l15) * 72 + kk * 32 + lg * 8]);
#pragma unroll
        for (int dn = 0; dn < 4; ++dn) {
          bf16x8 vf = *(const bf16x8*)(&Vts[cur][(dn * 16 + l15) * 64 +
                                               (((kk * 4 + lg) ^ swz) * 8)]);
#pragma unroll
          for (int qm = 0; qm < 2; ++qm)
            oacc[qm][dn] = mfma16(vf, pf[qm], oacc[qm][dn]);
        }
      }
      __builtin_amdgcn_s_setprio(0);
    }

    const bool segend = (kt == 4 * qt + 3);
    if (segend || i == 8) {
      if (pstart == 0 && segend) {
        // whole segment: finalize to Og
#pragma unroll
        for (int qm = 0; qm < 2; ++qm) {
          float lt = lrun[qm];                 // cross-lane sum (once per seg)
          lt += __shfl_xor(lt, 16);
          lt += __shfl_xor(lt, 32);
          float rinv = 1.0f / lt;
          int row = q0 + wq + qm * 16 + l15;
#pragma unroll
          for (int dn = 0; dn < 4; ++dn) {
            ushort4 ow;
            ow.x = f2bf(oacc[qm][dn][0] * rinv);
            ow.y = f2bf(oacc[qm][dn][1] * rinv);
            ow.z = f2bf(oacc[qm][dn][2] * rinv);
            ow.w = f2bf(oacc[qm][dn][3] * rinv);
            *(ushort4*)(Og + baseQ + (size_t)row * Dn + dn * 16 + lg * 4) = ow;
          }
        }
      } else {
        // piece: seg-initial -> slot qt; continuing -> slot 8+j
        const size_t slot = (size_t)bh * 24 + (pstart == 0 ? qt : 8 + j);
#pragma unroll
        for (int qm = 0; qm < 2; ++qm) {
          float lt = lrun[qm];
          lt += __shfl_xor(lt, 16);
          lt += __shfl_xor(lt, 32);
          int rl = wq + qm * 16 + l15;     // local row 0..255
#pragma unroll
          for (int dn = 0; dn < 4; ++dn) {
            ushort4 ow;
            ow.x = f2bf(oacc[qm][dn][0]);
            ow.y = f2bf(oacc[qm][dn][1]);
            ow.z = f2bf(oacc[qm][dn][2]);
            ow.w = f2bf(oacc[qm][dn][3]);
            *(ushort4*)(Pb + slot * 16384 + (size_t)rl * 64 + dn * 16 + lg * 4) = ow;
          }
          if (lg == 0) {
            Pml[slot * 512 + rl] = mrun[qm];
            Pml[slot * 512 + 256 + rl] = lt;
          }
        }
      }
      if (i < 8) {
        ++qt; kt = 0; pstart = 0;
        loadQ(qt);
#pragma unroll
        for (int qm = 0; qm < 2; ++qm) {
          mrun[qm] = -1e30f; lrun[qm] = 0.f;
#pragma unroll
          for (int dn = 0; dn < 4; ++dn) oacc[qm][dn] = f32x4{0.f, 0.f, 0.f, 0.f};
        }
      }
    } else {
      ++kt;
    }
    __syncthreads();
  }
}

// ---------------------------------------------------------------------------
// Merge <=4 pieces for split segments (exp2-domain weights).  Two-pass,
// array-free.  bid = qt*32 + bh (XCD locality); 512 threads: r = tid>>1
// (0..255), c32 = (tid&1)*32.
// ---------------------------------------------------------------------------
__global__ __launch_bounds__(512)
void attn_combine(const unsigned short* __restrict__ Pb,
                  const float* __restrict__ Pml,
                  unsigned short* __restrict__ Og) {
  const int bid = blockIdx.x;      // 0..255: qt*32 + bh
  const int qt = bid >> 5, bh = bid & 31;
  const int seg_s = 2 * qt * (qt + 1);
  const int seg_e = 2 * (qt + 1) * (qt + 2);
  const int js = seg_s / 9;
  const int je = (seg_e - 1) / 9;
  const int np = je - js + 1;
  if (np == 1) return;             // whole segment finalized in attn_part
  const int bb = bh >> 4, hh = bh & 15;
  const size_t baseQ = (size_t)bb * Sn * Dn + (size_t)hh * DKn;
  const int q0 = qt * 256;
  const int r = threadIdx.x >> 1;          // 0..255
  const int c32 = (threadIdx.x & 1) * 32;  // col half

  // pass 1: running max over pieces
  float M = -1e30f;
  for (int p = 0; p < np; ++p) {
    size_t slot = (size_t)bh * 24 + (p == 0 ? qt : 8 + js + p);
    M = fmaxf(M, Pml[slot * 512 + r]);
  }

  // pass 2: weighted accumulate
  float L = 0.f;
  float acc[32];
#pragma unroll
  for (int k = 0; k < 32; ++k) acc[k] = 0.f;
  for (int p = 0; p < np; ++p) {
    size_t slot = (size_t)bh * 24 + (p == 0 ? qt : 8 + js + p);
    float w = exp2a(Pml[slot * 512 + r] - M);
    L += Pml[slot * 512 + 256 + r] * w;
    const unsigned short* src = Pb + slot * 16384 + (size_t)r * 64 + c32;
#pragma unroll
    for (int k4 = 0; k4 < 8; ++k4) {
      ushort4 v = *(const ushort4*)(src + k4 * 4);
      acc[k4 * 4 + 0] += w * bf2f(v.x);
      acc[k4 * 4 + 1] += w * bf2f(v.y);
      acc[k4 * 4 + 2] += w * bf2f(v.z);
      acc[k4 * 4 + 3] += w * bf2f(v.w);
    }
  }

  float rinv = 1.0f / L;
#pragma unroll
  for (int k4 = 0; k4 < 8; ++k4) {
    ushort4 o;
    o.x = f2bf(acc[k4 * 4 + 0] * rinv);
    o.y = f2bf(acc[k4 * 4 + 1] * rinv);
    o.z = f2bf(acc[k4 * 4 + 2] * rinv);
    o.w = f2bf(acc[k4 * 4 + 3] * rinv);
    *(ushort4*)(Og + baseQ + (size_t)(q0 + r) * Dn + c32 + k4 * 4) = o;
  }
}

// ---------------------------------------------------------------------------
extern "C" void kernel_launch(void* const* d_in, const int* in_sizes, int n_in,
                              void* d_out, int out_size, void* d_ws, size_t ws_size,
                              hipStream_t stream) {
  const float* x  = (const float*)d_in[0];
  const float* Wq = (const float*)d_in[1];
  const float* Wk = (const float*)d_in[2];
  const float* Wv = (const float*)d_in[3];
  const float* Wo = (const float*)d_in[4];
  float* out = (float*)d_out;

  char* ws = (char*)d_ws;
  size_t off = 0;
  unsigned short* xb  = (unsigned short*)(ws + off); off += (size_t)Mrows * Dn * 2;
  unsigned short* wqb = (unsigned short*)(ws + off); off += (size_t)Dn * Dn * 2;
  unsigned short* wkb = (unsigned short*)(ws + off); off += (size_t)Dn * Dn * 2;
  unsigned short* wvb = (unsigned short*)(ws + off); off += (size_t)Dn * Dn * 2;
  unsigned short* wob = (unsigned short*)(ws + off); off += (size_t)Dn * Dn * 2;
  unsigned short* Qb  = (unsigned short*)(ws + off); off += (size_t)Mrows * Dn * 2;
  unsigned short* Kb  = (unsigned short*)(ws + off); off += (size_t)Mrows * Dn * 2;
  unsigned short* Vtb = (unsigned short*)(ws + off); off += (size_t)Mrows * Dn * 2;
  unsigned short* Ob  = (unsigned short*)(ws + off); off += (size_t)Mrows * Dn * 2;
  unsigned short* Pb  = (unsigned short*)(ws + off); off += (size_t)32 * 24 * 16384 * 2;
  float*          Pml = (float*)(ws + off);          off += (size_t)32 * 24 * 512 * 4;

  cvt_all<<<8192, 256, 0, stream>>>(x, Wq, Wk, Wv, Wo, xb, wqb, wkb, wvb, wob);
  gemm_qkv<<<768, 512, 0, stream>>>(xb, wqb, wkb, wvb, Qb, Kb, Vtb);
  attn_part<<<512, 512, 0, stream>>>(Qb, Kb, Vtb, Ob, Pb, Pml);
  attn_combine<<<256, 512, 0, stream>>>(Pb, Pml, Ob);
  gemm_out<<<dim3(Mrows / 64, Dn / 128), 256, 0, stream>>>(Ob, wob, out);
}

// Round 21
// 103.416 us; speedup vs baseline: 1.0041x; 1.0041x over previous
//
#include <hip/hip_runtime.h>
#include <hip/hip_bf16.h>

typedef __attribute__((ext_vector_type(4))) float f32x4;
typedef __attribute__((ext_vector_type(8))) short bf16x8;

// Problem constants (B=2, S=2048, D=1024, H=16, DK=64)
#define Bn 2
#define Sn 2048
#define Dn 1024
#define Hn 16
#define DKn 64
#define Mrows (Bn * Sn)   // 4096

__device__ __forceinline__ unsigned short f2bf(float f) {
  unsigned int x = __float_as_uint(f);
  x += 0x7fffu + ((x >> 16) & 1u);   // round-to-nearest-even
  return (unsigned short)(x >> 16);
}

__device__ __forceinline__ float bf2f(unsigned short u) {
  return __uint_as_float(((unsigned int)u) << 16);
}

__device__ __forceinline__ unsigned int cvtpk(float lo, float hi) {
  unsigned int r;
  asm("v_cvt_pk_bf16_f32 %0, %1, %2" : "=v"(r) : "v"(lo), "v"(hi));
  return r;
}

__device__ __forceinline__ float exp2a(float x) {   // native v_exp_f32 (2^x)
  float r;
  asm("v_exp_f32 %0, %1" : "=v"(r) : "v"(x));
  return r;
}

__device__ __forceinline__ f32x4 mfma16(bf16x8 a, bf16x8 b, f32x4 c) {
  return __builtin_amdgcn_mfma_f32_16x16x32_bf16(a, b, c, 0, 0, 0);
}

__device__ __forceinline__ f32x4 max4(f32x4 a, f32x4 b) {
  f32x4 r;
  r[0] = fmaxf(a[0], b[0]); r[1] = fmaxf(a[1], b[1]);
  r[2] = fmaxf(a[2], b[2]); r[3] = fmaxf(a[3], b[3]);
  return r;
}

__device__ __forceinline__ void gload_lds16(const unsigned short* g, unsigned short* l) {
  __builtin_amdgcn_global_load_lds(
      (const __attribute__((address_space(1))) void*)g,
      (__attribute__((address_space(3))) void*)l, 16, 0, 0);
}

// ---------------------------------------------------------------------------
// fused fp32 -> bf16 convert for x + 4 weights (one launch)
// ---------------------------------------------------------------------------
__global__ __launch_bounds__(256)
void cvt_all(const float* __restrict__ x,  const float* __restrict__ wq,
             const float* __restrict__ wk, const float* __restrict__ wv,
             const float* __restrict__ wo,
             unsigned short* __restrict__ xb,  unsigned short* __restrict__ wqb,
             unsigned short* __restrict__ wkb, unsigned short* __restrict__ wvb,
             unsigned short* __restrict__ wob) {
  int i = (blockIdx.x * 256 + threadIdx.x) * 4;
  const float* src; unsigned short* dst; int off;
  int r = i >> 20;
  if (r < 4)       { src = x;  dst = xb;  off = i; }
  else if (r == 4) { src = wq; dst = wqb; off = i & 1048575; }
  else if (r == 5) { src = wk; dst = wkb; off = i & 1048575; }
  else if (r == 6) { src = wv; dst = wvb; off = i & 1048575; }
  else             { src = wo; dst = wob; off = i & 1048575; }
  float4 v = *(const float4*)(src + off);
  ushort4 o;
  o.x = f2bf(v.x); o.y = f2bf(v.y); o.z = f2bf(v.z); o.w = f2bf(v.w);
  *(ushort4*)(dst + off) = o;
}

// ---------------------------------------------------------------------------
// 128x128-tile QKV GEMM, 8 WAVES (512 threads, wave-tile 32x64): BK=32,
// TRIPLE-buffered LDS (48 KB, 3 blocks/CU = 24 waves/CU), 1 raw barrier per
// step + counted vmcnt(2) (2 gloads/wave/stage, 2 stages in flight).
// Granule-XOR swizzle both sides.
// MODE 0: bf16, scaled 0.125*log2(e) (Q, exp2 domain) | 1: bf16 (K)
// MODE 2: bf16 Vt[b][h][d][s] transposed
// ---------------------------------------------------------------------------
template<int MODE>
__device__ __forceinline__ void gemm_body8(const unsigned short* __restrict__ A,
                                           const unsigned short* __restrict__ W,
                                           unsigned short* __restrict__ Cb,
                                           unsigned short* As,   // [3][128*32]
                                           unsigned short* Bs,   // [3][128*32]
                                           int row0, int col0) {
  const int K = Dn, N = Dn;
  const int tid  = threadIdx.x;
  const int wid  = tid >> 6;               // 0..7
  const int lane = tid & 63;
  const int l15  = lane & 15;
  const int lg   = lane >> 4;
  const int wr = (wid >> 1) * 32;          // 4 M-waves x 32 rows
  const int wc = (wid & 1) * 64;           // 2 N-waves x 64 cols

  f32x4 acc[2][4] = {};

  const int lrow2 = lane >> 2;             // row within chunk 0..15
  const int gs    = (lane & 3) ^ ((lane >> 3) & 3);  // pre-swizzled src granule
  const int swzr  = (l15 >> 1) & 3;        // read-side XOR

  // 16 chunks: 0..7 = A rows (16 each), 8..15 = B rows (16 each); 2/wave.
  auto stage = [&](int kt, int b) {
#pragma unroll
    for (int q = 0; q < 2; ++q) {
      int id = wid * 2 + q;                // 0..15
      if (id < 8) {
        int r = id * 16 + lrow2;
        gload_lds16(A + (size_t)(row0 + r) * K + kt + gs * 8,
                    &As[b * 4096 + id * 512]);
      } else {
        int r = (id - 8) * 16 + lrow2;
        gload_lds16(W + (size_t)(col0 + r) * K + kt + gs * 8,
                    &Bs[b * 4096 + (id - 8) * 512]);
      }
    }
  };

  auto compute = [&](int b) {
    bf16x8 af[2], bfr[4];
#pragma unroll
    for (int m = 0; m < 2; ++m)
      af[m] = *(const bf16x8*)(&As[b * 4096 + (wr + m * 16 + l15) * 32 +
                                   ((lg ^ swzr) * 8)]);
#pragma unroll
    for (int n = 0; n < 4; ++n)
      bfr[n] = *(const bf16x8*)(&Bs[b * 4096 + (wc + n * 16 + l15) * 32 +
                                    ((lg ^ swzr) * 8)]);
    __builtin_amdgcn_s_setprio(1);
#pragma unroll
    for (int m = 0; m < 2; ++m)
#pragma unroll
      for (int n = 0; n < 4; ++n)
        acc[m][n] = mfma16(af[m], bfr[n], acc[m][n]);
    __builtin_amdgcn_s_setprio(0);
  };

  stage(0, 0);
  stage(32, 1);
  int cb = 0;
#pragma unroll 1
  for (int t = 0; t < 32; ++t) {
    if (t < 31) asm volatile("s_waitcnt vmcnt(2)" ::: "memory");
    else        asm volatile("s_waitcnt vmcnt(0)" ::: "memory");
    __builtin_amdgcn_sched_barrier(0);
    __builtin_amdgcn_s_barrier();
    __builtin_amdgcn_sched_barrier(0);
    if (t <= 29) {
      int sb = cb + 2; if (sb >= 3) sb -= 3;
      stage((t + 2) * 32, sb);
    }
    compute(cb);
    ++cb; if (cb == 3) cb = 0;
  }

#pragma unroll
  for (int m = 0; m < 2; ++m)
#pragma unroll
    for (int n = 0; n < 4; ++n) {
      int r0 = row0 + wr + m * 16 + lg * 4;
      int c  = col0 + wc + n * 16 + l15;
      if (MODE == 2) {
        int b = r0 >> 11, s = r0 & 2047;
        int h = c >> 6,  d = c & 63;
        ushort4 pw;
        pw.x = f2bf(acc[m][n][0]); pw.y = f2bf(acc[m][n][1]);
        pw.z = f2bf(acc[m][n][2]); pw.w = f2bf(acc[m][n][3]);
        *(ushort4*)(Cb + ((((size_t)b * Hn + h) * DKn + d) << 11) + s) = pw;
      } else {
        const float sc = (MODE == 0) ? 0.18033688f : 1.0f;  // Q: 0.125*log2e
#pragma unroll
        for (int j = 0; j < 4; ++j)
          Cb[(size_t)(r0 + j) * N + c] = f2bf(acc[m][n][j] * sc);
      }
    }
}

// XCD panel mapping: fid%24 = panel (y = panel&7, z = panel>>3), fid/24 = x.
__global__ __launch_bounds__(512, 3)
void gemm_qkv(const unsigned short* __restrict__ A,
              const unsigned short* __restrict__ W0,
              const unsigned short* __restrict__ W1,
              const unsigned short* __restrict__ W2,
              unsigned short* __restrict__ C0,
              unsigned short* __restrict__ C1,
              unsigned short* __restrict__ C2) {
  __shared__ unsigned short As[3 * 128 * 32];
  __shared__ unsigned short Bs[3 * 128 * 32];
  const int fid = blockIdx.x;          // 0..767
  const int panel = fid % 24;
  const int row0 = (fid / 24) * 128;
  const int col0 = (panel & 7) * 128;
  const int z = panel >> 3;
  if (z == 0)      gemm_body8<0>(A, W0, C0, As, Bs, row0, col0);
  else if (z == 1) gemm_body8<1>(A, W1, C1, As, Bs, row0, col0);
  else             gemm_body8<2>(A, W2, C2, As, Bs, row0, col0);
}

// ---------------------------------------------------------------------------
// Output projection GEMM: 64x128 tiles, 512 blocks (2/CU exact, zero tail),
// BK=32, TRIPLE-buffered (36 KB), 1 barrier/step + counted vmcnt(3).
// Wave-tile 32x64; 12 staging chunks = 3 per wave.  fp32 output.
// ---------------------------------------------------------------------------
__global__ __launch_bounds__(256, 4)
void gemm_out(const unsigned short* __restrict__ A,
              const unsigned short* __restrict__ W,
              float* __restrict__ C) {
  __shared__ unsigned short As[3 * 64 * 32];    // 12 KB
  __shared__ unsigned short Bs[3 * 128 * 32];   // 24 KB
  const int K = Dn, N = Dn;
  const int tid  = threadIdx.x;
  const int wid  = tid >> 6;
  const int lane = tid & 63;
  const int l15  = lane & 15;
  const int lg   = lane >> 4;
  const int row0 = blockIdx.x * 64;
  const int col0 = blockIdx.y * 128;
  const int wr = (wid >> 1) * 32;
  const int wc = (wid & 1) * 64;

  f32x4 acc[2][4] = {};

  const int lrow2 = lane >> 2;               // row within chunk 0..15
  const int gs    = (lane & 3) ^ ((lane >> 3) & 3);  // pre-swizzled src granule
  const int swzr  = (l15 >> 1) & 3;          // read-side XOR

  // 12 chunks: 0..3 = A rows (16 each), 4..11 = B rows (16 each).
  auto stage = [&](int kt, int b) {
#pragma unroll
    for (int q = 0; q < 3; ++q) {
      int id = wid * 3 + q;                  // 0..11
      if (id < 4) {
        int r = id * 16 + lrow2;
        gload_lds16(A + (size_t)(row0 + r) * K + kt + gs * 8,
                    &As[b * 2048 + id * 512]);
      } else {
        int r = (id - 4) * 16 + lrow2;
        gload_lds16(W + (size_t)(col0 + r) * K + kt + gs * 8,
                    &Bs[b * 4096 + (id - 4) * 512]);
      }
    }
  };

  auto compute = [&](int b) {
    bf16x8 af[2], bfr[4];
#pragma unroll
    for (int m = 0; m < 2; ++m)
      af[m] = *(const bf16x8*)(&As[b * 2048 + (wr + m * 16 + l15) * 32 +
                                   ((lg ^ swzr) * 8)]);
#pragma unroll
    for (int n = 0; n < 4; ++n)
      bfr[n] = *(const bf16x8*)(&Bs[b * 4096 + (wc + n * 16 + l15) * 32 +
                                    ((lg ^ swzr) * 8)]);
    __builtin_amdgcn_s_setprio(1);
#pragma unroll
    for (int m = 0; m < 2; ++m)
#pragma unroll
      for (int n = 0; n < 4; ++n)
        acc[m][n] = mfma16(af[m], bfr[n], acc[m][n]);
    __builtin_amdgcn_s_setprio(0);
  };

  stage(0, 0);
  stage(32, 1);
  int cb = 0;
#pragma unroll 1
  for (int t = 0; t < 32; ++t) {
    if (t < 31) asm volatile("s_waitcnt vmcnt(3)" ::: "memory");
    else        asm volatile("s_waitcnt vmcnt(0)" ::: "memory");
    __builtin_amdgcn_sched_barrier(0);
    __builtin_amdgcn_s_barrier();
    __builtin_amdgcn_sched_barrier(0);
    if (t <= 29) {
      int sb = cb + 2; if (sb >= 3) sb -= 3;
      stage((t + 2) * 32, sb);
    }
    compute(cb);
    ++cb; if (cb == 3) cb = 0;
  }

#pragma unroll
  for (int m = 0; m < 2; ++m)
#pragma unroll
    for (int n = 0; n < 4; ++n) {
      int r0 = row0 + wr + m * 16 + lg * 4;
      int c  = col0 + wc + n * 16 + l15;
#pragma unroll
      for (int j = 0; j < 4; ++j)
        C[(size_t)(r0 + j) * N + c] = acc[m][n][j];
    }
}

// ---------------------------------------------------------------------------
// Flash attention (causal), swapped-operand, UNIFORM KV-SPLIT, QBLK=256.
// 512 blocks x 512 threads (8 waves x 32 q-rows, 2 qm groups/wave).
// Per bh: 8 q-tiles of 256 rows; kv tiles per qt = 4qt+4; total 144 = 16x9
// -> block j owns exactly 9 consecutive tiles.  K/Vt staged in LDS (parity
// dbuf, gload_lds, XOR granule swizzle).  Whole segments finalize to Og;
// pieces -> slot bh*24 + (initial? qt : 8+j); attn_combine merges <=4.
// exp2-domain softmax, lane-local max, deferred per-lane sum.
// ---------------------------------------------------------------------------
__global__ __launch_bounds__(512, 4)
void attn_part(const unsigned short* __restrict__ Qg,
               const unsigned short* __restrict__ Kg,
               const unsigned short* __restrict__ Vtg,
               unsigned short* __restrict__ Og,
               unsigned short* __restrict__ Pb,
               float* __restrict__ Pml) {
  const int bid = blockIdx.x;      // 0..511
  const int bh = bid & 31;         // bh%8 -> XCD locality
  const int j  = bid >> 5;         // 0..15: which 9-tile run
  const int bb = bh >> 4, hh = bh & 15;
  const int tid = threadIdx.x, wid = tid >> 6, lane = tid & 63;  // wid 0..7
  const int l15 = lane & 15, lg = lane >> 4;
  const int wq = wid * 32;
  const size_t baseQ = (size_t)bb * Sn * Dn + (size_t)hh * DKn;
  const size_t baseV = (size_t)bh * DKn * Sn;

  __shared__ unsigned short Ks[2][64 * 64];   // K tile  [key][d], parity dbuf
  __shared__ unsigned short Vts[2][64 * 64];  // Vt tile [d][key], parity dbuf
  __shared__ unsigned short Ps[8][32 * 72];   // per-wave P [q][key], pad 72

  const int lrow  = lane >> 3;
  const int sgran = (lane & 7) ^ lrow;
  const int swz   = l15 & 7;

  // locate starting segment: seg_s(qt) = 2qt(qt+1), len 4(qt+1)
  const int g0 = 9 * j;
  int qt = 0;
  while (2 * (qt + 1) * (qt + 2) <= g0) ++qt;
  int kt = g0 - 2 * qt * (qt + 1);

  int sqt = qt, skt = kt;
  auto stage = [&](int t, int b) {
    const int k0 = t << 6;
    gload_lds16(Kg + baseQ + (size_t)(k0 + wid * 8 + lrow) * Dn + sgran * 8,
                &Ks[b][wid * 512]);
    gload_lds16(Vtg + baseV + (size_t)(wid * 8 + lrow) * Sn + k0 + sgran * 8,
                &Vts[b][wid * 512]);
  };
  auto advs = [&]() { ++skt; if (skt == 4 * sqt + 4) { skt = 0; ++sqt; } };

  stage(skt, 0); advs();
  __syncthreads();

  bf16x8 qf[2][2];
  auto loadQ = [&](int qtile) {
    const int q0 = qtile * 256;
#pragma unroll
    for (int qm = 0; qm < 2; ++qm)
#pragma unroll
      for (int kd = 0; kd < 2; ++kd)
        qf[qm][kd] = *(const bf16x8*)(Qg + baseQ +
                     (size_t)(q0 + wq + qm * 16 + l15) * Dn + kd * 32 + lg * 8);
  };
  loadQ(qt);

  f32x4 oacc[2][4] = {};
  float mrun[2] = {-1e30f, -1e30f};
  float lrun[2] = {0.f, 0.f};     // per-lane partials (deferred cross-lane sum)
  int pstart = kt;                 // first kv-tile of current piece

  for (int i = 0; i < 9; ++i) {
    const int cur = i & 1;
    if (i < 8) { stage(skt, cur ^ 1); advs(); }
    const int k0 = kt << 6;
    const int q0 = qt << 8;

    if (k0 <= q0 + wq + 31) {      // wave-level causal skip (wave-uniform)
      f32x4 sf[2][4] = {};
      __builtin_amdgcn_s_setprio(1);
#pragma unroll
      for (int kn = 0; kn < 4; ++kn)
#pragma unroll
        for (int kd = 0; kd < 2; ++kd) {
          bf16x8 kf = *(const bf16x8*)(&Ks[cur][(kn * 16 + l15) * 64 +
                                              (((kd * 4 + lg) ^ swz) * 8)]);
          sf[0][kn] = mfma16(kf, qf[0][kd], sf[0][kn]);
          sf[1][kn] = mfma16(kf, qf[1][kd], sf[1][kn]);
        }
      __builtin_amdgcn_s_setprio(0);

      if (k0 + 63 > q0 + wq) {     // causal mask (diag-overlap tiles)
#pragma unroll
        for (int qm = 0; qm < 2; ++qm) {
          int qq = q0 + wq + qm * 16 + l15;
#pragma unroll
          for (int kn = 0; kn < 4; ++kn)
#pragma unroll
            for (int jj = 0; jj < 4; ++jj) {
              int key = k0 + kn * 16 + lg * 4 + jj;
              if (key > qq) sf[qm][kn][jj] = -1e30f;
            }
        }
      }

#pragma unroll
      for (int qm = 0; qm < 2; ++qm) {
        // lane-local max of own 16 values (no cross-lane in common path)
        f32x4 mm = max4(max4(sf[qm][0], sf[qm][1]), max4(sf[qm][2], sf[qm][3]));
        float tl = fmaxf(fmaxf(mm[0], mm[1]), fmaxf(mm[2], mm[3]));
        if (__any(tl > mrun[qm] + 11.5f)) {   // defer-max THR (log2 domain)
          float t = tl;
          t = fmaxf(t, __shfl_xor(t, 16));
          t = fmaxf(t, __shfl_xor(t, 32));
          float mnew = fmaxf(mrun[qm], t);
          float corr = exp2a(mrun[qm] - mnew);
          mrun[qm] = mnew;
          lrun[qm] *= corr;
#pragma unroll
          for (int dn = 0; dn < 4; ++dn) oacc[qm][dn] *= corr;
        }
        const float m = mrun[qm];
#pragma unroll
        for (int kn = 0; kn < 4; ++kn) {
#pragma unroll
          for (int jj = 0; jj < 4; ++jj)
            sf[qm][kn][jj] = exp2a(sf[qm][kn][jj] - m);
          uint2 pw;
          pw.x = cvtpk(sf[qm][kn][0], sf[qm][kn][1]);
          pw.y = cvtpk(sf[qm][kn][2], sf[qm][kn][3]);
          *(uint2*)(&Ps[wid][(qm * 16 + l15) * 72 + kn * 16 + lg * 4]) = pw;
        }
        f32x4 sv = (sf[qm][0] + sf[qm][1]) + (sf[qm][2] + sf[qm][3]);
        lrun[qm] += (sv[0] + sv[1]) + (sv[2] + sv[3]);   // per-lane partial
      }

      __builtin_amdgcn_s_setprio(1);
#pragma unroll
      for (int kk = 0; kk < 2; ++kk) {
        bf16x8 pf[2];
#pragma unroll
        for (int qm = 0; qm < 2; ++qm)
          pf[qm] = *(const bf16x8*)(&Ps[wid][(qm * 16 + l15) * 72 + kk * 32 + lg * 8]);
#pragma unroll
        for (int dn = 0; dn < 4; ++dn) {
          bf16x8 vf = *(const bf16x8*)(&Vts[cur][(dn * 16 + l15) * 64 +
                                               (((kk * 4 + lg) ^ swz) * 8)]);
#pragma unroll
          for (int qm = 0; qm < 2; ++qm)
            oacc[qm][dn] = mfma16(vf, pf[qm], oacc[qm][dn]);
        }
      }
      __builtin_amdgcn_s_setprio(0);
    }

    const bool segend = (kt == 4 * qt + 3);
    if (segend || i == 8) {
      if (pstart == 0 && segend) {
        // whole segment: finalize to Og
#pragma unroll
        for (int qm = 0; qm < 2; ++qm) {
          float lt = lrun[qm];                 // cross-lane sum (once per seg)
          lt += __shfl_xor(lt, 16);
          lt += __shfl_xor(lt, 32);
          float rinv = 1.0f / lt;
          int row = q0 + wq + qm * 16 + l15;
#pragma unroll
          for (int dn = 0; dn < 4; ++dn) {
            ushort4 ow;
            ow.x = f2bf(oacc[qm][dn][0] * rinv);
            ow.y = f2bf(oacc[qm][dn][1] * rinv);
            ow.z = f2bf(oacc[qm][dn][2] * rinv);
            ow.w = f2bf(oacc[qm][dn][3] * rinv);
            *(ushort4*)(Og + baseQ + (size_t)row * Dn + dn * 16 + lg * 4) = ow;
          }
        }
      } else {
        // piece: seg-initial -> slot qt; continuing -> slot 8+j
        const size_t slot = (size_t)bh * 24 + (pstart == 0 ? qt : 8 + j);
#pragma unroll
        for (int qm = 0; qm < 2; ++qm) {
          float lt = lrun[qm];
          lt += __shfl_xor(lt, 16);
          lt += __shfl_xor(lt, 32);
          int rl = wq + qm * 16 + l15;     // local row 0..255
#pragma unroll
          for (int dn = 0; dn < 4; ++dn) {
            ushort4 ow;
            ow.x = f2bf(oacc[qm][dn][0]);
            ow.y = f2bf(oacc[qm][dn][1]);
            ow.z = f2bf(oacc[qm][dn][2]);
            ow.w = f2bf(oacc[qm][dn][3]);
            *(ushort4*)(Pb + slot * 16384 + (size_t)rl * 64 + dn * 16 + lg * 4) = ow;
          }
          if (lg == 0) {
            Pml[slot * 512 + rl] = mrun[qm];
            Pml[slot * 512 + 256 + rl] = lt;
          }
        }
      }
      if (i < 8) {
        ++qt; kt = 0; pstart = 0;
        loadQ(qt);
#pragma unroll
        for (int qm = 0; qm < 2; ++qm) {
          mrun[qm] = -1e30f; lrun[qm] = 0.f;
#pragma unroll
          for (int dn = 0; dn < 4; ++dn) oacc[qm][dn] = f32x4{0.f, 0.f, 0.f, 0.f};
        }
      }
    } else {
      ++kt;
    }
    __syncthreads();
  }
}

// ---------------------------------------------------------------------------
// Merge <=4 pieces for split segments (exp2-domain weights).  Two-pass,
// array-free.  bid = qt*32 + bh (XCD locality); 512 threads: r = tid>>1
// (0..255), c32 = (tid&1)*32.
// ---------------------------------------------------------------------------
__global__ __launch_bounds__(512)
void attn_combine(const unsigned short* __restrict__ Pb,
                  const float* __restrict__ Pml,
                  unsigned short* __restrict__ Og) {
  const int bid = blockIdx.x;      // 0..255: qt*32 + bh
  const int qt = bid >> 5, bh = bid & 31;
  const int seg_s = 2 * qt * (qt + 1);
  const int seg_e = 2 * (qt + 1) * (qt + 2);
  const int js = seg_s / 9;
  const int je = (seg_e - 1) / 9;
  const int np = je - js + 1;
  if (np == 1) return;             // whole segment finalized in attn_part
  const int bb = bh >> 4, hh = bh & 15;
  const size_t baseQ = (size_t)bb * Sn * Dn + (size_t)hh * DKn;
  const int q0 = qt * 256;
  const int r = threadIdx.x >> 1;          // 0..255
  const int c32 = (threadIdx.x & 1) * 32;  // col half

  // pass 1: running max over pieces
  float M = -1e30f;
  for (int p = 0; p < np; ++p) {
    size_t slot = (size_t)bh * 24 + (p == 0 ? qt : 8 + js + p);
    M = fmaxf(M, Pml[slot * 512 + r]);
  }

  // pass 2: weighted accumulate
  float L = 0.f;
  float acc[32];
#pragma unroll
  for (int k = 0; k < 32; ++k) acc[k] = 0.f;
  for (int p = 0; p < np; ++p) {
    size_t slot = (size_t)bh * 24 + (p == 0 ? qt : 8 + js + p);
    float w = exp2a(Pml[slot * 512 + r] - M);
    L += Pml[slot * 512 + 256 + r] * w;
    const unsigned short* src = Pb + slot * 16384 + (size_t)r * 64 + c32;
#pragma unroll
    for (int k4 = 0; k4 < 8; ++k4) {
      ushort4 v = *(const ushort4*)(src + k4 * 4);
      acc[k4 * 4 + 0] += w * bf2f(v.x);
      acc[k4 * 4 + 1] += w * bf2f(v.y);
      acc[k4 * 4 + 2] += w * bf2f(v.z);
      acc[k4 * 4 + 3] += w * bf2f(v.w);
    }
  }

  float rinv = 1.0f / L;
#pragma unroll
  for (int k4 = 0; k4 < 8; ++k4) {
    ushort4 o;
    o.x = f2bf(acc[k4 * 4 + 0] * rinv);
    o.y = f2bf(acc[k4 * 4 + 1] * rinv);
    o.z = f2bf(acc[k4 * 4 + 2] * rinv);
    o.w = f2bf(acc[k4 * 4 + 3] * rinv);
    *(ushort4*)(Og + baseQ + (size_t)(q0 + r) * Dn + c32 + k4 * 4) = o;
  }
}

// ---------------------------------------------------------------------------
extern "C" void kernel_launch(void* const* d_in, const int* in_sizes, int n_in,
                              void* d_out, int out_size, void* d_ws, size_t ws_size,
                              hipStream_t stream) {
  const float* x  = (const float*)d_in[0];
  const float* Wq = (const float*)d_in[1];
  const float* Wk = (const float*)d_in[2];
  const float* Wv = (const float*)d_in[3];
  const float* Wo = (const float*)d_in[4];
  float* out = (float*)d_out;

  char* ws = (char*)d_ws;
  size_t off = 0;
  unsigned short* xb  = (unsigned short*)(ws + off); off += (size_t)Mrows * Dn * 2;
  unsigned short* wqb = (unsigned short*)(ws + off); off += (size_t)Dn * Dn * 2;
  unsigned short* wkb = (unsigned short*)(ws + off); off += (size_t)Dn * Dn * 2;
  unsigned short* wvb = (unsigned short*)(ws + off); off += (size_t)Dn * Dn * 2;
  unsigned short* wob = (unsigned short*)(ws + off); off += (size_t)Dn * Dn * 2;
  unsigned short* Qb  = (unsigned short*)(ws + off); off += (size_t)Mrows * Dn * 2;
  unsigned short* Kb  = (unsigned short*)(ws + off); off += (size_t)Mrows * Dn * 2;
  unsigned short* Vtb = (unsigned short*)(ws + off); off += (size_t)Mrows * Dn * 2;
  unsigned short* Ob  = (unsigned short*)(ws + off); off += (size_t)Mrows * Dn * 2;
  unsigned short* Pb  = (unsigned short*)(ws + off); off += (size_t)32 * 24 * 16384 * 2;
  float*          Pml = (float*)(ws + off);          off += (size_t)32 * 24 * 512 * 4;

  cvt_all<<<8192, 256, 0, stream>>>(x, Wq, Wk, Wv, Wo, xb, wqb, wkb, wvb, wob);
  gemm_qkv<<<768, 512, 0, stream>>>(xb, wqb, wkb, wvb, Qb, Kb, Vtb);
  attn_part<<<512, 512, 0, stream>>>(Qb, Kb, Vtb, Ob, Pb, Pml);
  attn_combine<<<256, 512, 0, stream>>>(Pb, Pml, Ob);
  gemm_out<<<dim3(Mrows / 64, Dn / 128), 256, 0, stream>>>(Ob, wob, out);
}